// Round 6
// baseline (719.161 us; speedup 1.0000x reference)
//
#include <hip/hip_runtime.h>
#include <hip/hip_bf16.h>

// Problem constants (RelKDAdapter_60284160966709)
#define D_SRC 256
#define D_REL 128

typedef short bf16x8 __attribute__((ext_vector_type(8)));
typedef float f32x4 __attribute__((ext_vector_type(4)));

__device__ __forceinline__ unsigned short f2bf(float f) {
  unsigned u = __float_as_uint(f);
  unsigned r = 0x7FFFu + ((u >> 16) & 1u);
  return (unsigned short)((u + r) >> 16);
}

// 2x fp32 -> packed bf16 pair via v_cvt_pk_bf16_f32 (compiler-generated, RNE)
__device__ __forceinline__ unsigned cvt2(float lo, float hi) {
  __hip_bfloat162 h = __float22bfloat162_rn(make_float2(lo, hi));
  return *reinterpret_cast<unsigned*>(&h);
}

__device__ __forceinline__ bf16x8 pack8(float4 a, float4 b) {
  union { unsigned u[4]; bf16x8 v; } r;
  r.u[0] = cvt2(a.x, a.y);
  r.u[1] = cvt2(a.z, a.w);
  r.u[2] = cvt2(b.x, b.y);
  r.u[3] = cvt2(b.z, b.w);
  return r.v;
}

// ---------------- W -> bf16 in MFMA B-fragment order ----------------
// Wfrag layout: [ks (8)][j (8)][lane (64)][8 bf16], 16B per (ks,j,lane) slot.
// Frag semantics (mfma_f32_16x16x32_bf16 B operand): col n = j*16 + (lane&15),
// k = ks*32 + (lane>>4)*8 + m.  Value = bf16(W[k][n]) (W stored [K=256][N=128]).
// Layout harness-verified rounds 1-5 (passed, absmax 0.03125).
__global__ __launch_bounds__(256) void convert_wt(
    const float* __restrict__ W, unsigned short* __restrict__ Wfrag) {
  int idx = blockIdx.x * 256 + threadIdx.x;  // 0..4095 (8*8*64)
  int lane = idx & 63;
  int j = (idx >> 6) & 7;
  int ks = idx >> 9;
  int n = j * 16 + (lane & 15);
  int k = ks * 32 + (lane >> 4) * 8;
  bf16x8 o;
#pragma unroll
  for (int m = 0; m < 8; ++m)
    o[m] = (short)f2bf(W[(size_t)(k + m) * D_REL + n]);
  *(bf16x8*)(Wfrag + (size_t)idx * 8) = o;  // 16B store, frag-linear
}

#define GBM 128

// ---------------- MFMA GEMM v6: fp32 A, register-prefetch PINNED ----------------
// r5 failure: compiler sank the 16 upfront A-loads into the k-loop (VGPR=52
// proved it). Fix: sched_barrier(0) after the load block -- a compile-time
// scheduling fence nothing can cross; loads are not rematerializable, so the
// 64-VGPR block must stay live. One __syncthreads for B; then cvt+MFMA stream.
__global__ __launch_bounds__(512, 2) void gemm_mfma(
    const float* __restrict__ A,               // [M, 256] fp32
    const unsigned short* __restrict__ Wfrag,  // [8][8][64][8] bf16 frag-order
    float* __restrict__ C,                     // [M, 128] fp32 out
    unsigned short* __restrict__ Cbf,          // [M, 128] bf16 copy
    int M, int write_bf) {
  __shared__ unsigned short Bs[8 * 8 * 64 * 8];  // 64 KB, frag-linear

  const int t = threadIdx.x;
  const int w = t >> 6;        // wave 0..7
  const int lane = t & 63;
  const int quad = lane >> 4;
  const int l16 = lane & 15;
  const int wrow = blockIdx.x * GBM + w * 16;

  const int r0 = wrow + l16;
  const int r0c = (r0 < M) ? r0 : (M - 1);   // clamp: branchless, always-valid loads
  const float* a0 = A + (size_t)r0c * D_SRC + quad * 8;

  // --- Issue all 16 A float4 loads back-to-back (64 VGPR in flight) ---
  float4 afp[16];
#pragma unroll
  for (int ks = 0; ks < 8; ++ks) {
    afp[2 * ks]     = *(const float4*)(a0 + ks * 32);
    afp[2 * ks + 1] = *(const float4*)(a0 + ks * 32 + 4);
  }
  // Pin: nothing may be scheduled across this point -> loads stay up front.
  __builtin_amdgcn_sched_barrier(0);

  // --- Stage all of B once: 4096 x 16B slots, 8 per thread, coalesced ---
#pragma unroll
  for (int i = 0; i < 8; ++i) {
    int s = t + 512 * i;
    *(uint4*)(Bs + (size_t)s * 8) = *(const uint4*)(Wfrag + (size_t)s * 8);
  }
  __syncthreads();  // only barrier; drains A loads + B staging together

  f32x4 acc[8];
#pragma unroll
  for (int j = 0; j < 8; ++j) acc[j] = (f32x4)(0.0f);

  // --- cvt + pure LDS-read + MFMA stream ---
#pragma unroll
  for (int ks = 0; ks < 8; ++ks) {
    bf16x8 af = pack8(afp[2 * ks], afp[2 * ks + 1]);
#pragma unroll
    for (int j = 0; j < 8; ++j) {
      bf16x8 bfr = *(const bf16x8*)(Bs + (((size_t)ks * 8 + j) * 64 + lane) * 8);
      acc[j] = __builtin_amdgcn_mfma_f32_16x16x32_bf16(af, bfr, acc[j], 0, 0, 0);
    }
  }

  // Epilogue: C/D layout col=lane&15, row=quad*4+reg
#pragma unroll
  for (int r = 0; r < 4; ++r) {
    int grow = wrow + quad * 4 + r;
    if (grow < M) {
#pragma unroll
      for (int j = 0; j < 8; ++j) {
        int gcol = j * 16 + l16;
        float val = acc[j][r];
        C[(size_t)grow * D_REL + gcol] = val;
        if (write_bf) Cbf[(size_t)grow * D_REL + gcol] = f2bf(val);
      }
    }
  }
}

// ---------------- Degree count ----------------
__global__ __launch_bounds__(256) void deg_count(
    const int* __restrict__ edge_row, int E, int* __restrict__ cnt) {
  int i = blockIdx.x * blockDim.x + threadIdx.x;
  if (i < E) atomicAdd(&cnt[edge_row[i]], 1);
}

// ---------------- Exclusive scan of cnt -> row_ptr (+ fused deg/inv_deg) ----------------
#define SCAN_B 256

__global__ __launch_bounds__(SCAN_B) void scan1(
    const int* __restrict__ cnt, int n,
    int* __restrict__ row_ptr, int* __restrict__ block_sums,
    float* __restrict__ deg_out, float* __restrict__ inv_deg) {
  __shared__ int s[SCAN_B];
  int i = blockIdx.x * SCAN_B + threadIdx.x;
  int v = (i < n) ? cnt[i] : 0;
  if (i < n) {
    float d = (float)(v > 1 ? v : 1);
    deg_out[i] = d;
    inv_deg[i] = 1.0f / d;
  }
  s[threadIdx.x] = v;
  __syncthreads();
#pragma unroll
  for (int off = 1; off < SCAN_B; off <<= 1) {
    int add = (threadIdx.x >= off) ? s[threadIdx.x - off] : 0;
    __syncthreads();
    s[threadIdx.x] += add;
    __syncthreads();
  }
  if (i < n) row_ptr[i] = s[threadIdx.x] - v;
  if (threadIdx.x == SCAN_B - 1) block_sums[blockIdx.x] = s[SCAN_B - 1];
}

__global__ __launch_bounds__(512) void scan2(
    int* __restrict__ block_sums, int nblocks) {
  __shared__ int s[512];
  int v = (threadIdx.x < nblocks) ? block_sums[threadIdx.x] : 0;
  s[threadIdx.x] = v;
  __syncthreads();
#pragma unroll
  for (int off = 1; off < 512; off <<= 1) {
    int add = (threadIdx.x >= off) ? s[threadIdx.x - off] : 0;
    __syncthreads();
    s[threadIdx.x] += add;
    __syncthreads();
  }
  if (threadIdx.x < nblocks) block_sums[threadIdx.x] = s[threadIdx.x] - v;
}

__global__ __launch_bounds__(SCAN_B) void scan3(
    int* __restrict__ row_ptr, const int* __restrict__ block_sums,
    int* __restrict__ cursor, int n, int E) {
  int i = blockIdx.x * SCAN_B + threadIdx.x;
  if (i < n) {
    int v = row_ptr[i] + block_sums[blockIdx.x];
    row_ptr[i] = v;
    cursor[i] = v;
  }
  if (i == 0) row_ptr[n] = E;
}

// ---------------- Scatter edges into CSR order (packed: col | row_local<<20) ----------------
// row_local = dst row & 31 (aggregate blocks own aligned 32-row groups).
// col < 2^20 (N_SRC = 100000), row_local < 32 -> fits bits 20..24.
__global__ __launch_bounds__(256) void scatter_edges(
    const int* __restrict__ edge_row, const int* __restrict__ edge_col,
    int* __restrict__ cursor, int* __restrict__ sorted_col, int E) {
  int e = blockIdx.x * blockDim.x + threadIdx.x;
  if (e < E) {
    int r = edge_row[e];
    int pos = atomicAdd(&cursor[r], 1);
    sorted_col[pos] = edge_col[e] | ((r & 31) << 20);
  }
}

// ---------------- Aggregate v6: block of 8 waves per 32 dst rows, LDS accumulator ----------------
// Edge-parallel over the 32-row span (8 edges in flight per block vs 2 for
// wave-per-row): each wave-iteration handles one edge; 64 lanes gather one
// dword (2 bf16) each = 256B/edge, accumulate via ds_add_f32 into
// accum[row_local][128] (16 KB). Epilogue: coalesced *inv_deg write.
__global__ __launch_bounds__(512) void aggregate_lds(
    const int* __restrict__ row_ptr, const int* __restrict__ sorted_packed,
    const unsigned short* __restrict__ srcb, const float* __restrict__ inv_deg,
    float* __restrict__ dst, int n) {
  __shared__ float accum[32 * 128];  // 16 KB

  const int t = threadIdx.x;
  const int r0 = blockIdx.x * 32;

  // zero accumulator
#pragma unroll
  for (int i = 0; i < 8; ++i) accum[t + 512 * i] = 0.0f;
  __syncthreads();

  const int rend = (r0 + 32 < n) ? (r0 + 32) : n;
  const int beg = row_ptr[r0];
  const int end = row_ptr[rend];
  const int w = t >> 6;
  const int lane = t & 63;

  for (int e = beg + w; e < end; e += 8) {
    unsigned p = (unsigned)sorted_packed[e];   // broadcast across the wave
    int col = (int)(p & 0xFFFFFu);
    int rl = (int)(p >> 20);
    unsigned u = *(const unsigned*)(srcb + (size_t)col * D_REL + lane * 2);
    atomicAdd(&accum[rl * 128 + lane * 2],     __uint_as_float(u << 16));
    atomicAdd(&accum[rl * 128 + lane * 2 + 1], __uint_as_float(u & 0xffff0000u));
  }
  __syncthreads();

  // Epilogue: 32 rows x 128 = 1024 float4, 2 per thread, coalesced
#pragma unroll
  for (int i = 0; i < 2; ++i) {
    int idx = t + 512 * i;       // 0..1023 float4 index
    int rl = idx >> 5;           // 0..31
    int c4 = (idx & 31) * 4;     // 0..124
    int r = r0 + rl;
    if (r < n) {
      float wgt = inv_deg[r];
      const float* s = accum + rl * 128 + c4;
      float4 o;
      o.x = s[0] * wgt; o.y = s[1] * wgt; o.z = s[2] * wgt; o.w = s[3] * wgt;
      *(float4*)(dst + (size_t)r * D_REL + c4) = o;
    }
  }
}

// ---------------- CSR aggregate (fp32 gather fallback; strips packed row bits) ----------------
__global__ __launch_bounds__(256) void aggregate_csr(
    const int* __restrict__ row_ptr, const int* __restrict__ sorted_packed,
    const float* __restrict__ src_proj, const float* __restrict__ inv_deg,
    float* __restrict__ dst, int n) {
  int wave = (blockIdx.x * blockDim.x + threadIdx.x) >> 6;
  int lane = threadIdx.x & 63;
  if (wave >= n) return;
  int beg = row_ptr[wave];
  int end = row_ptr[wave + 1];
  const float* base = src_proj + lane * 2;
  float ax = 0.f, ay = 0.f, bx = 0.f, by = 0.f;
  int e = beg;
  for (; e + 1 < end; e += 2) {
    int c0 = sorted_packed[e] & 0xFFFFF;
    int c1 = sorted_packed[e + 1] & 0xFFFFF;
    float2 v0 = *(const float2*)(base + (size_t)c0 * D_REL);
    float2 v1 = *(const float2*)(base + (size_t)c1 * D_REL);
    ax += v0.x; ay += v0.y;
    bx += v1.x; by += v1.y;
  }
  if (e < end) {
    int c0 = sorted_packed[e] & 0xFFFFF;
    float2 v0 = *(const float2*)(base + (size_t)c0 * D_REL);
    ax += v0.x; ay += v0.y;
  }
  float wgt = inv_deg[wave];
  float2 o;
  o.x = (ax + bx) * wgt;
  o.y = (ay + by) * wgt;
  *(float2*)(dst + (size_t)wave * D_REL + lane * 2) = o;
}

extern "C" void kernel_launch(void* const* d_in, const int* in_sizes, int n_in,
                              void* d_out, int out_size, void* d_ws, size_t ws_size,
                              hipStream_t stream) {
  const float* x_src = (const float*)d_in[0];
  // d_in[1] = x_dst, d_in[3] = W_dst: dead (dst_proj is deleted in reference)
  const float* W_src = (const float*)d_in[2];
  const int* edge_row = (const int*)d_in[4];
  const int* edge_col = (const int*)d_in[5];

  const int M = in_sizes[0] / D_SRC;   // N_SRC = 100000
  const int N = in_sizes[1] / 64;      // N_DST = 100000
  const int E = in_sizes[4];           // 640000

  float* out = (float*)d_out;
  float* out_dst = out;                                  // [N, 128]
  float* out_src_proj = out + (size_t)N * D_REL;         // [M, 128]
  float* out_deg = out_src_proj + (size_t)M * D_REL;     // [N]

  // Workspace layout (256B-aligned slabs)
  char* ws = (char*)d_ws;
  size_t off = 0;
  auto alloc = [&](size_t bytes) {
    char* p = ws + off;
    off = (off + bytes + 255) & ~(size_t)255;
    return p;
  };
  int* cnt        = (int*)alloc((size_t)N * sizeof(int));
  int* row_ptr    = (int*)alloc((size_t)(N + 1) * sizeof(int));
  int* cursor     = (int*)alloc((size_t)N * sizeof(int));
  int* sorted_col = (int*)alloc((size_t)E * sizeof(int));
  float* inv_deg  = (float*)alloc((size_t)N * sizeof(float));
  int* block_sums = (int*)alloc(512 * sizeof(int));
  unsigned short* WT = (unsigned short*)alloc((size_t)D_REL * D_SRC * sizeof(unsigned short));
  unsigned short* src_bf = (unsigned short*)alloc((size_t)M * D_REL * sizeof(unsigned short));
  const bool use_bf = (ws_size >= off);

  const int scan_blocks = (N + SCAN_B - 1) / SCAN_B;  // 391 <= 512

  hipMemsetAsync(cnt, 0, (size_t)N * sizeof(int), stream);

  // W bf16, MFMA B-fragment order
  convert_wt<<<16, 256, 0, stream>>>(W_src, WT);

  // Degree
  deg_count<<<(E + 255) / 256, 256, 0, stream>>>(edge_row, E, cnt);

  // Exclusive scan cnt -> row_ptr (+ deg/inv_deg fused); cursor = row_ptr
  scan1<<<scan_blocks, SCAN_B, 0, stream>>>(cnt, N, row_ptr, block_sums,
                                            out_deg, inv_deg);
  scan2<<<1, 512, 0, stream>>>(block_sums, scan_blocks);
  scan3<<<scan_blocks, SCAN_B, 0, stream>>>(row_ptr, block_sums, cursor, N, E);

  // CSR scatter (packed col | row_local<<20)
  scatter_edges<<<(E + 255) / 256, 256, 0, stream>>>(edge_row, edge_col, cursor,
                                                     sorted_col, E);

  // MFMA GEMM (fused fp32->bf16 cvt): src_proj fp32 + bf16 copy for the gather
  gemm_mfma<<<(M + GBM - 1) / GBM, 512, 0, stream>>>(
      x_src, WT, out_src_proj, src_bf, M, use_bf ? 1 : 0);

  // Aggregate: block of 8 waves per 32 dst rows, LDS accumulator
  if (use_bf) {
    aggregate_lds<<<(N + 31) / 32, 512, 0, stream>>>(row_ptr, sorted_col, src_bf,
                                                     inv_deg, out_dst, N);
  } else {
    aggregate_csr<<<(N + 3) / 4, 256, 0, stream>>>(row_ptr, sorted_col, out_src_proj,
                                                   inv_deg, out_dst, N);
  }
}

// Round 7
// 323.648 us; speedup vs baseline: 2.2220x; 2.2220x over previous
//
#include <hip/hip_runtime.h>
#include <hip/hip_bf16.h>

// Problem constants (RelKDAdapter_60284160966709)
#define D_SRC 256
#define D_REL 128

typedef short bf16x8 __attribute__((ext_vector_type(8)));
typedef float f32x4 __attribute__((ext_vector_type(4)));

__device__ __forceinline__ unsigned short f2bf(float f) {
  unsigned u = __float_as_uint(f);
  unsigned r = 0x7FFFu + ((u >> 16) & 1u);
  return (unsigned short)((u + r) >> 16);
}

// 2x fp32 -> packed bf16 pair via v_cvt_pk_bf16_f32 (compiler-generated, RNE)
__device__ __forceinline__ unsigned cvt2(float lo, float hi) {
  __hip_bfloat162 h = __float22bfloat162_rn(make_float2(lo, hi));
  return *reinterpret_cast<unsigned*>(&h);
}

__device__ __forceinline__ bf16x8 pack8(float4 a, float4 b) {
  union { unsigned u[4]; bf16x8 v; } r;
  r.u[0] = cvt2(a.x, a.y);
  r.u[1] = cvt2(a.z, a.w);
  r.u[2] = cvt2(b.x, b.y);
  r.u[3] = cvt2(b.z, b.w);
  return r.v;
}

// ---------------- W -> bf16 in MFMA B-fragment order ----------------
// Wfrag layout: [ks (8)][j (8)][lane (64)][8 bf16], 16B per (ks,j,lane) slot.
// Frag semantics (mfma_f32_16x16x32_bf16 B operand): col n = j*16 + (lane&15),
// k = ks*32 + (lane>>4)*8 + m.  Value = bf16(W[k][n]) (W stored [K=256][N=128]).
// Layout harness-verified rounds 1-6 (passed, absmax 0.03125).
__global__ __launch_bounds__(256) void convert_wt(
    const float* __restrict__ W, unsigned short* __restrict__ Wfrag) {
  int idx = blockIdx.x * 256 + threadIdx.x;  // 0..4095 (8*8*64)
  int lane = idx & 63;
  int j = (idx >> 6) & 7;
  int ks = idx >> 9;
  int n = j * 16 + (lane & 15);
  int k = ks * 32 + (lane >> 4) * 8;
  bf16x8 o;
#pragma unroll
  for (int m = 0; m < 8; ++m)
    o[m] = (short)f2bf(W[(size_t)(k + m) * D_REL + n]);
  *(bf16x8*)(Wfrag + (size_t)idx * 8) = o;  // 16B store, frag-linear
}

#define GBM 128

// ---------------- MFMA GEMM: fp32 A, register-prefetch pinned (r6 structure) ----------------
__global__ __launch_bounds__(512, 2) void gemm_mfma(
    const float* __restrict__ A,               // [M, 256] fp32
    const unsigned short* __restrict__ Wfrag,  // [8][8][64][8] bf16 frag-order
    float* __restrict__ C,                     // [M, 128] fp32 out
    unsigned short* __restrict__ Cbf,          // [M, 128] bf16 copy
    int M, int write_bf) {
  __shared__ unsigned short Bs[8 * 8 * 64 * 8];  // 64 KB, frag-linear

  const int t = threadIdx.x;
  const int w = t >> 6;        // wave 0..7
  const int lane = t & 63;
  const int quad = lane >> 4;
  const int l16 = lane & 15;
  const int wrow = blockIdx.x * GBM + w * 16;

  const int r0 = wrow + l16;
  const int r0c = (r0 < M) ? r0 : (M - 1);   // clamp: branchless, always-valid loads
  const float* a0 = A + (size_t)r0c * D_SRC + quad * 8;

  // --- Issue all 16 A float4 loads back-to-back (64 VGPR in flight) ---
  float4 afp[16];
#pragma unroll
  for (int ks = 0; ks < 8; ++ks) {
    afp[2 * ks]     = *(const float4*)(a0 + ks * 32);
    afp[2 * ks + 1] = *(const float4*)(a0 + ks * 32 + 4);
  }
  // Pin: nothing may be scheduled across this point -> loads stay up front.
  __builtin_amdgcn_sched_barrier(0);

  // --- Stage all of B once: 4096 x 16B slots, 8 per thread, coalesced ---
#pragma unroll
  for (int i = 0; i < 8; ++i) {
    int s = t + 512 * i;
    *(uint4*)(Bs + (size_t)s * 8) = *(const uint4*)(Wfrag + (size_t)s * 8);
  }
  __syncthreads();  // only barrier; drains A loads + B staging together

  f32x4 acc[8];
#pragma unroll
  for (int j = 0; j < 8; ++j) acc[j] = (f32x4)(0.0f);

  // --- cvt + pure LDS-read + MFMA stream ---
#pragma unroll
  for (int ks = 0; ks < 8; ++ks) {
    bf16x8 af = pack8(afp[2 * ks], afp[2 * ks + 1]);
#pragma unroll
    for (int j = 0; j < 8; ++j) {
      bf16x8 bfr = *(const bf16x8*)(Bs + (((size_t)ks * 8 + j) * 64 + lane) * 8);
      acc[j] = __builtin_amdgcn_mfma_f32_16x16x32_bf16(af, bfr, acc[j], 0, 0, 0);
    }
  }

  // Epilogue: C/D layout col=lane&15, row=quad*4+reg
#pragma unroll
  for (int r = 0; r < 4; ++r) {
    int grow = wrow + quad * 4 + r;
    if (grow < M) {
#pragma unroll
      for (int j = 0; j < 8; ++j) {
        int gcol = j * 16 + l16;
        float val = acc[j][r];
        C[(size_t)grow * D_REL + gcol] = val;
        if (write_bf) Cbf[(size_t)grow * D_REL + gcol] = f2bf(val);
      }
    }
  }
}

// ---------------- Degree count ----------------
__global__ __launch_bounds__(256) void deg_count(
    const int* __restrict__ edge_row, int E, int* __restrict__ cnt) {
  int i = blockIdx.x * blockDim.x + threadIdx.x;
  if (i < E) atomicAdd(&cnt[edge_row[i]], 1);
}

// ---------------- Exclusive scan of cnt -> row_ptr (+ fused deg/inv_deg) ----------------
#define SCAN_B 256

__global__ __launch_bounds__(SCAN_B) void scan1(
    const int* __restrict__ cnt, int n,
    int* __restrict__ row_ptr, int* __restrict__ block_sums,
    float* __restrict__ deg_out, float* __restrict__ inv_deg) {
  __shared__ int s[SCAN_B];
  int i = blockIdx.x * SCAN_B + threadIdx.x;
  int v = (i < n) ? cnt[i] : 0;
  if (i < n) {
    float d = (float)(v > 1 ? v : 1);
    deg_out[i] = d;
    inv_deg[i] = 1.0f / d;
  }
  s[threadIdx.x] = v;
  __syncthreads();
#pragma unroll
  for (int off = 1; off < SCAN_B; off <<= 1) {
    int add = (threadIdx.x >= off) ? s[threadIdx.x - off] : 0;
    __syncthreads();
    s[threadIdx.x] += add;
    __syncthreads();
  }
  if (i < n) row_ptr[i] = s[threadIdx.x] - v;
  if (threadIdx.x == SCAN_B - 1) block_sums[blockIdx.x] = s[SCAN_B - 1];
}

__global__ __launch_bounds__(512) void scan2(
    int* __restrict__ block_sums, int nblocks) {
  __shared__ int s[512];
  int v = (threadIdx.x < nblocks) ? block_sums[threadIdx.x] : 0;
  s[threadIdx.x] = v;
  __syncthreads();
#pragma unroll
  for (int off = 1; off < 512; off <<= 1) {
    int add = (threadIdx.x >= off) ? s[threadIdx.x - off] : 0;
    __syncthreads();
    s[threadIdx.x] += add;
    __syncthreads();
  }
  if (threadIdx.x < nblocks) block_sums[threadIdx.x] = s[threadIdx.x] - v;
}

__global__ __launch_bounds__(SCAN_B) void scan3(
    int* __restrict__ row_ptr, const int* __restrict__ block_sums,
    int* __restrict__ cursor, int n, int E) {
  int i = blockIdx.x * SCAN_B + threadIdx.x;
  if (i < n) {
    int v = row_ptr[i] + block_sums[blockIdx.x];
    row_ptr[i] = v;
    cursor[i] = v;
  }
  if (i == 0) row_ptr[n] = E;
}

// ---------------- Scatter edges into CSR order ----------------
__global__ __launch_bounds__(256) void scatter_edges(
    const int* __restrict__ edge_row, const int* __restrict__ edge_col,
    int* __restrict__ cursor, int* __restrict__ sorted_col, int E) {
  int e = blockIdx.x * blockDim.x + threadIdx.x;
  if (e < E) {
    int r = edge_row[e];
    int pos = atomicAdd(&cursor[r], 1);
    sorted_col[pos] = edge_col[e];
  }
}

// ---------------- CSR aggregate (bf16 gather): wave per dst row, 4 edges/iter ----------------
// Wave split into four 16-lane quarters; each quarter gathers a different
// edge's row at 16 B/lane (uint4 = 8 bf16) -> 4 edges in flight, avg trip
// count deg/4 ~= 1.6. Cross-quarter combine via shfl_xor(16|32); quarter 0
// writes 2x float4 (512 B contiguous per wave).
__global__ __launch_bounds__(256) void aggregate_csr_bf16(
    const int* __restrict__ row_ptr, const int* __restrict__ sorted_col,
    const unsigned short* __restrict__ srcb, const float* __restrict__ inv_deg,
    float* __restrict__ dst, int n) {
  int wave = (blockIdx.x * blockDim.x + threadIdx.x) >> 6;
  int lane = threadIdx.x & 63;
  if (wave >= n) return;
  int beg = row_ptr[wave];
  int end = row_ptr[wave + 1];
  const int q = lane >> 4;      // quarter 0..3: which edge of the group
  const int l16 = lane & 15;    // elements l16*8 .. l16*8+7
  const unsigned short* base = srcb + l16 * 8;

  float a0 = 0.f, a1 = 0.f, a2 = 0.f, a3 = 0.f;
  float a4 = 0.f, a5 = 0.f, a6 = 0.f, a7 = 0.f;
  for (int e = beg; e < end; e += 4) {
    if (e + q < end) {          // uniform within a quarter
      int col = sorted_col[e + q];
      uint4 u = *(const uint4*)(base + (size_t)col * D_REL);
      a0 += __uint_as_float(u.x << 16);
      a1 += __uint_as_float(u.x & 0xffff0000u);
      a2 += __uint_as_float(u.y << 16);
      a3 += __uint_as_float(u.y & 0xffff0000u);
      a4 += __uint_as_float(u.z << 16);
      a5 += __uint_as_float(u.z & 0xffff0000u);
      a6 += __uint_as_float(u.w << 16);
      a7 += __uint_as_float(u.w & 0xffff0000u);
    }
  }
  // combine quarters: lane L += L^16, then += L^32
  a0 += __shfl_xor(a0, 16); a1 += __shfl_xor(a1, 16);
  a2 += __shfl_xor(a2, 16); a3 += __shfl_xor(a3, 16);
  a4 += __shfl_xor(a4, 16); a5 += __shfl_xor(a5, 16);
  a6 += __shfl_xor(a6, 16); a7 += __shfl_xor(a7, 16);
  a0 += __shfl_xor(a0, 32); a1 += __shfl_xor(a1, 32);
  a2 += __shfl_xor(a2, 32); a3 += __shfl_xor(a3, 32);
  a4 += __shfl_xor(a4, 32); a5 += __shfl_xor(a5, 32);
  a6 += __shfl_xor(a6, 32); a7 += __shfl_xor(a7, 32);

  if (q == 0) {
    float wgt = inv_deg[wave];
    float* o = dst + (size_t)wave * D_REL + l16 * 8;
    float4 v0, v1;
    v0.x = a0 * wgt; v0.y = a1 * wgt; v0.z = a2 * wgt; v0.w = a3 * wgt;
    v1.x = a4 * wgt; v1.y = a5 * wgt; v1.z = a6 * wgt; v1.w = a7 * wgt;
    *(float4*)(o) = v0;
    *(float4*)(o + 4) = v1;
  }
}

// ---------------- CSR aggregate (fp32 gather fallback) ----------------
__global__ __launch_bounds__(256) void aggregate_csr(
    const int* __restrict__ row_ptr, const int* __restrict__ sorted_col,
    const float* __restrict__ src_proj, const float* __restrict__ inv_deg,
    float* __restrict__ dst, int n) {
  int wave = (blockIdx.x * blockDim.x + threadIdx.x) >> 6;
  int lane = threadIdx.x & 63;
  if (wave >= n) return;
  int beg = row_ptr[wave];
  int end = row_ptr[wave + 1];
  const float* base = src_proj + lane * 2;
  float ax = 0.f, ay = 0.f, bx = 0.f, by = 0.f;
  int e = beg;
  for (; e + 1 < end; e += 2) {
    int c0 = sorted_col[e];
    int c1 = sorted_col[e + 1];
    float2 v0 = *(const float2*)(base + (size_t)c0 * D_REL);
    float2 v1 = *(const float2*)(base + (size_t)c1 * D_REL);
    ax += v0.x; ay += v0.y;
    bx += v1.x; by += v1.y;
  }
  if (e < end) {
    int c0 = sorted_col[e];
    float2 v0 = *(const float2*)(base + (size_t)c0 * D_REL);
    ax += v0.x; ay += v0.y;
  }
  float wgt = inv_deg[wave];
  float2 o;
  o.x = (ax + bx) * wgt;
  o.y = (ay + by) * wgt;
  *(float2*)(dst + (size_t)wave * D_REL + lane * 2) = o;
}

extern "C" void kernel_launch(void* const* d_in, const int* in_sizes, int n_in,
                              void* d_out, int out_size, void* d_ws, size_t ws_size,
                              hipStream_t stream) {
  const float* x_src = (const float*)d_in[0];
  // d_in[1] = x_dst, d_in[3] = W_dst: dead (dst_proj is deleted in reference)
  const float* W_src = (const float*)d_in[2];
  const int* edge_row = (const int*)d_in[4];
  const int* edge_col = (const int*)d_in[5];

  const int M = in_sizes[0] / D_SRC;   // N_SRC = 100000
  const int N = in_sizes[1] / 64;      // N_DST = 100000
  const int E = in_sizes[4];           // 640000

  float* out = (float*)d_out;
  float* out_dst = out;                                  // [N, 128]
  float* out_src_proj = out + (size_t)N * D_REL;         // [M, 128]
  float* out_deg = out_src_proj + (size_t)M * D_REL;     // [N]

  // Workspace layout (256B-aligned slabs)
  char* ws = (char*)d_ws;
  size_t off = 0;
  auto alloc = [&](size_t bytes) {
    char* p = ws + off;
    off = (off + bytes + 255) & ~(size_t)255;
    return p;
  };
  int* cnt        = (int*)alloc((size_t)N * sizeof(int));
  int* row_ptr    = (int*)alloc((size_t)(N + 1) * sizeof(int));
  int* cursor     = (int*)alloc((size_t)N * sizeof(int));
  int* sorted_col = (int*)alloc((size_t)E * sizeof(int));
  float* inv_deg  = (float*)alloc((size_t)N * sizeof(float));
  int* block_sums = (int*)alloc(512 * sizeof(int));
  unsigned short* WT = (unsigned short*)alloc((size_t)D_REL * D_SRC * sizeof(unsigned short));
  unsigned short* src_bf = (unsigned short*)alloc((size_t)M * D_REL * sizeof(unsigned short));
  const bool use_bf = (ws_size >= off);

  const int scan_blocks = (N + SCAN_B - 1) / SCAN_B;  // 391 <= 512

  hipMemsetAsync(cnt, 0, (size_t)N * sizeof(int), stream);

  // W bf16, MFMA B-fragment order
  convert_wt<<<16, 256, 0, stream>>>(W_src, WT);

  // Degree
  deg_count<<<(E + 255) / 256, 256, 0, stream>>>(edge_row, E, cnt);

  // Exclusive scan cnt -> row_ptr (+ deg/inv_deg fused); cursor = row_ptr
  scan1<<<scan_blocks, SCAN_B, 0, stream>>>(cnt, N, row_ptr, block_sums,
                                            out_deg, inv_deg);
  scan2<<<1, 512, 0, stream>>>(block_sums, scan_blocks);
  scan3<<<scan_blocks, SCAN_B, 0, stream>>>(row_ptr, block_sums, cursor, N, E);

  // CSR scatter
  scatter_edges<<<(E + 255) / 256, 256, 0, stream>>>(edge_row, edge_col, cursor,
                                                     sorted_col, E);

  // MFMA GEMM (fused fp32->bf16 cvt): src_proj fp32 + bf16 copy for the gather
  gemm_mfma<<<(M + GBM - 1) / GBM, 512, 0, stream>>>(
      x_src, WT, out_src_proj, src_bf, M, use_bf ? 1 : 0);

  // Gather-aggregate: 1 wave per dst row, 4 edges/iter
  if (use_bf) {
    aggregate_csr_bf16<<<(N + 3) / 4, 256, 0, stream>>>(row_ptr, sorted_col, src_bf,
                                                        inv_deg, out_dst, N);
  } else {
    aggregate_csr<<<(N + 3) / 4, 256, 0, stream>>>(row_ptr, sorted_col, out_src_proj,
                                                   inv_deg, out_dst, N);
  }
}

// Round 8
// 322.897 us; speedup vs baseline: 2.2272x; 1.0023x over previous
//
#include <hip/hip_runtime.h>
#include <hip/hip_bf16.h>

// Problem constants (RelKDAdapter_60284160966709)
#define D_SRC 256
#define D_REL 128

typedef short bf16x8 __attribute__((ext_vector_type(8)));
typedef float f32x4 __attribute__((ext_vector_type(4)));

__device__ __forceinline__ unsigned short f2bf(float f) {
  unsigned u = __float_as_uint(f);
  unsigned r = 0x7FFFu + ((u >> 16) & 1u);
  return (unsigned short)((u + r) >> 16);
}

// 2x fp32 -> packed bf16 pair via v_cvt_pk_bf16_f32 (compiler-generated, RNE)
__device__ __forceinline__ unsigned cvt2(float lo, float hi) {
  __hip_bfloat162 h = __float22bfloat162_rn(make_float2(lo, hi));
  return *reinterpret_cast<unsigned*>(&h);
}

__device__ __forceinline__ bf16x8 pack8(float4 a, float4 b) {
  union { unsigned u[4]; bf16x8 v; } r;
  r.u[0] = cvt2(a.x, a.y);
  r.u[1] = cvt2(a.z, a.w);
  r.u[2] = cvt2(b.x, b.y);
  r.u[3] = cvt2(b.z, b.w);
  return r.v;
}

// ---------------- W -> bf16 in MFMA B-fragment order ----------------
// Wfrag layout: [ks (8)][j (8)][lane (64)][8 bf16], 16B per (ks,j,lane) slot.
// Frag semantics (mfma_f32_16x16x32_bf16 B operand): col n = j*16 + (lane&15),
// k = ks*32 + (lane>>4)*8 + m.  Value = bf16(W[k][n]) (W stored [K=256][N=128]).
// Layout harness-verified rounds 1-7 (passed, absmax 0.03125).
__global__ __launch_bounds__(256) void convert_wt(
    const float* __restrict__ W, unsigned short* __restrict__ Wfrag) {
  int idx = blockIdx.x * 256 + threadIdx.x;  // 0..4095 (8*8*64)
  int lane = idx & 63;
  int j = (idx >> 6) & 7;
  int ks = idx >> 9;
  int n = j * 16 + (lane & 15);
  int k = ks * 32 + (lane >> 4) * 8;
  bf16x8 o;
#pragma unroll
  for (int m = 0; m < 8; ++m)
    o[m] = (short)f2bf(W[(size_t)(k + m) * D_REL + n]);
  *(bf16x8*)(Wfrag + (size_t)idx * 8) = o;  // 16B store, frag-linear
}

#define GBM 128

// ---------------- MFMA GEMM v8: fp32 A, register-prefetch pinned via volatile asm ----------------
// r5/r7 failure: compiler sank the 16 upfront A-loads into the k-loop both with
// and without sched_barrier (VGPR=52 both rounds -- sinking happens at IR level,
// below the MI-scheduler fence). Fix: volatile empty-asm consumer per loaded
// component (rule-#17 keep-alive). Volatile asm is unmovable/undeletable and
// requires the value materialized in a VGPR -> all 16 loads are issued together
// here and the 64-VGPR block stays live. MFMA stream then has zero global loads.
__global__ __launch_bounds__(512, 2) void gemm_mfma(
    const float* __restrict__ A,               // [M, 256] fp32
    const unsigned short* __restrict__ Wfrag,  // [8][8][64][8] bf16 frag-order
    float* __restrict__ C,                     // [M, 128] fp32 out
    unsigned short* __restrict__ Cbf,          // [M, 128] bf16 copy
    int M, int write_bf) {
  __shared__ unsigned short Bs[8 * 8 * 64 * 8];  // 64 KB, frag-linear

  const int t = threadIdx.x;
  const int w = t >> 6;        // wave 0..7
  const int lane = t & 63;
  const int quad = lane >> 4;
  const int l16 = lane & 15;
  const int wrow = blockIdx.x * GBM + w * 16;

  const int r0 = wrow + l16;
  const int r0c = (r0 < M) ? r0 : (M - 1);   // clamp: branchless, always-valid loads
  const float* a0 = A + (size_t)r0c * D_SRC + quad * 8;

  // --- Issue all 16 A float4 loads back-to-back (64 VGPR in flight) ---
  float4 afp[16];
#pragma unroll
  for (int ks = 0; ks < 8; ++ks) {
    afp[2 * ks]     = *(const float4*)(a0 + ks * 32);
    afp[2 * ks + 1] = *(const float4*)(a0 + ks * 32 + 4);
  }
  // IR-level pin: volatile asm consumes every component -> loads must complete
  // here and values stay resident; nothing can sink them into the k-loop.
#pragma unroll
  for (int i = 0; i < 16; ++i)
    asm volatile("" :: "v"(afp[i].x), "v"(afp[i].y), "v"(afp[i].z), "v"(afp[i].w));

  // --- Stage all of B once: 4096 x 16B slots, 8 per thread, coalesced ---
#pragma unroll
  for (int i = 0; i < 8; ++i) {
    int s = t + 512 * i;
    *(uint4*)(Bs + (size_t)s * 8) = *(const uint4*)(Wfrag + (size_t)s * 8);
  }
  __syncthreads();  // only barrier

  f32x4 acc[8];
#pragma unroll
  for (int j = 0; j < 8; ++j) acc[j] = (f32x4)(0.0f);

  // --- cvt + pure LDS-read + MFMA stream ---
#pragma unroll
  for (int ks = 0; ks < 8; ++ks) {
    bf16x8 af = pack8(afp[2 * ks], afp[2 * ks + 1]);
#pragma unroll
    for (int j = 0; j < 8; ++j) {
      bf16x8 bfr = *(const bf16x8*)(Bs + (((size_t)ks * 8 + j) * 64 + lane) * 8);
      acc[j] = __builtin_amdgcn_mfma_f32_16x16x32_bf16(af, bfr, acc[j], 0, 0, 0);
    }
  }

  // Epilogue: C/D layout col=lane&15, row=quad*4+reg
#pragma unroll
  for (int r = 0; r < 4; ++r) {
    int grow = wrow + quad * 4 + r;
    if (grow < M) {
#pragma unroll
      for (int j = 0; j < 8; ++j) {
        int gcol = j * 16 + l16;
        float val = acc[j][r];
        C[(size_t)grow * D_REL + gcol] = val;
        if (write_bf) Cbf[(size_t)grow * D_REL + gcol] = f2bf(val);
      }
    }
  }
}

// ---------------- Degree count ----------------
__global__ __launch_bounds__(256) void deg_count(
    const int* __restrict__ edge_row, int E, int* __restrict__ cnt) {
  int i = blockIdx.x * blockDim.x + threadIdx.x;
  if (i < E) atomicAdd(&cnt[edge_row[i]], 1);
}

// ---------------- Exclusive scan of cnt -> row_ptr (+ fused deg/inv_deg) ----------------
#define SCAN_B 256

__global__ __launch_bounds__(SCAN_B) void scan1(
    const int* __restrict__ cnt, int n,
    int* __restrict__ row_ptr, int* __restrict__ block_sums,
    float* __restrict__ deg_out, float* __restrict__ inv_deg) {
  __shared__ int s[SCAN_B];
  int i = blockIdx.x * SCAN_B + threadIdx.x;
  int v = (i < n) ? cnt[i] : 0;
  if (i < n) {
    float d = (float)(v > 1 ? v : 1);
    deg_out[i] = d;
    inv_deg[i] = 1.0f / d;
  }
  s[threadIdx.x] = v;
  __syncthreads();
#pragma unroll
  for (int off = 1; off < SCAN_B; off <<= 1) {
    int add = (threadIdx.x >= off) ? s[threadIdx.x - off] : 0;
    __syncthreads();
    s[threadIdx.x] += add;
    __syncthreads();
  }
  if (i < n) row_ptr[i] = s[threadIdx.x] - v;
  if (threadIdx.x == SCAN_B - 1) block_sums[blockIdx.x] = s[SCAN_B - 1];
}

__global__ __launch_bounds__(512) void scan2(
    int* __restrict__ block_sums, int nblocks) {
  __shared__ int s[512];
  int v = (threadIdx.x < nblocks) ? block_sums[threadIdx.x] : 0;
  s[threadIdx.x] = v;
  __syncthreads();
#pragma unroll
  for (int off = 1; off < 512; off <<= 1) {
    int add = (threadIdx.x >= off) ? s[threadIdx.x - off] : 0;
    __syncthreads();
    s[threadIdx.x] += add;
    __syncthreads();
  }
  if (threadIdx.x < nblocks) block_sums[threadIdx.x] = s[threadIdx.x] - v;
}

__global__ __launch_bounds__(SCAN_B) void scan3(
    int* __restrict__ row_ptr, const int* __restrict__ block_sums,
    int* __restrict__ cursor, int n, int E) {
  int i = blockIdx.x * SCAN_B + threadIdx.x;
  if (i < n) {
    int v = row_ptr[i] + block_sums[blockIdx.x];
    row_ptr[i] = v;
    cursor[i] = v;
  }
  if (i == 0) row_ptr[n] = E;
}

// ---------------- Scatter edges into CSR order ----------------
__global__ __launch_bounds__(256) void scatter_edges(
    const int* __restrict__ edge_row, const int* __restrict__ edge_col,
    int* __restrict__ cursor, int* __restrict__ sorted_col, int E) {
  int e = blockIdx.x * blockDim.x + threadIdx.x;
  if (e < E) {
    int r = edge_row[e];
    int pos = atomicAdd(&cursor[r], 1);
    sorted_col[pos] = edge_col[e];
  }
}

// ---------------- CSR aggregate (bf16 gather): wave per dst row, 4 edges/iter ----------------
__global__ __launch_bounds__(256) void aggregate_csr_bf16(
    const int* __restrict__ row_ptr, const int* __restrict__ sorted_col,
    const unsigned short* __restrict__ srcb, const float* __restrict__ inv_deg,
    float* __restrict__ dst, int n) {
  int wave = (blockIdx.x * blockDim.x + threadIdx.x) >> 6;
  int lane = threadIdx.x & 63;
  if (wave >= n) return;
  int beg = row_ptr[wave];
  int end = row_ptr[wave + 1];
  const int q = lane >> 4;      // quarter 0..3: which edge of the group
  const int l16 = lane & 15;    // elements l16*8 .. l16*8+7
  const unsigned short* base = srcb + l16 * 8;

  float a0 = 0.f, a1 = 0.f, a2 = 0.f, a3 = 0.f;
  float a4 = 0.f, a5 = 0.f, a6 = 0.f, a7 = 0.f;
  for (int e = beg; e < end; e += 4) {
    if (e + q < end) {          // uniform within a quarter
      int col = sorted_col[e + q];
      uint4 u = *(const uint4*)(base + (size_t)col * D_REL);
      a0 += __uint_as_float(u.x << 16);
      a1 += __uint_as_float(u.x & 0xffff0000u);
      a2 += __uint_as_float(u.y << 16);
      a3 += __uint_as_float(u.y & 0xffff0000u);
      a4 += __uint_as_float(u.z << 16);
      a5 += __uint_as_float(u.z & 0xffff0000u);
      a6 += __uint_as_float(u.w << 16);
      a7 += __uint_as_float(u.w & 0xffff0000u);
    }
  }
  // combine quarters: lane L += L^16, then += L^32
  a0 += __shfl_xor(a0, 16); a1 += __shfl_xor(a1, 16);
  a2 += __shfl_xor(a2, 16); a3 += __shfl_xor(a3, 16);
  a4 += __shfl_xor(a4, 16); a5 += __shfl_xor(a5, 16);
  a6 += __shfl_xor(a6, 16); a7 += __shfl_xor(a7, 16);
  a0 += __shfl_xor(a0, 32); a1 += __shfl_xor(a1, 32);
  a2 += __shfl_xor(a2, 32); a3 += __shfl_xor(a3, 32);
  a4 += __shfl_xor(a4, 32); a5 += __shfl_xor(a5, 32);
  a6 += __shfl_xor(a6, 32); a7 += __shfl_xor(a7, 32);

  if (q == 0) {
    float wgt = inv_deg[wave];
    float* o = dst + (size_t)wave * D_REL + l16 * 8;
    float4 v0, v1;
    v0.x = a0 * wgt; v0.y = a1 * wgt; v0.z = a2 * wgt; v0.w = a3 * wgt;
    v1.x = a4 * wgt; v1.y = a5 * wgt; v1.z = a6 * wgt; v1.w = a7 * wgt;
    *(float4*)(o) = v0;
    *(float4*)(o + 4) = v1;
  }
}

// ---------------- CSR aggregate (fp32 gather fallback) ----------------
__global__ __launch_bounds__(256) void aggregate_csr(
    const int* __restrict__ row_ptr, const int* __restrict__ sorted_col,
    const float* __restrict__ src_proj, const float* __restrict__ inv_deg,
    float* __restrict__ dst, int n) {
  int wave = (blockIdx.x * blockDim.x + threadIdx.x) >> 6;
  int lane = threadIdx.x & 63;
  if (wave >= n) return;
  int beg = row_ptr[wave];
  int end = row_ptr[wave + 1];
  const float* base = src_proj + lane * 2;
  float ax = 0.f, ay = 0.f, bx = 0.f, by = 0.f;
  int e = beg;
  for (; e + 1 < end; e += 2) {
    int c0 = sorted_col[e];
    int c1 = sorted_col[e + 1];
    float2 v0 = *(const float2*)(base + (size_t)c0 * D_REL);
    float2 v1 = *(const float2*)(base + (size_t)c1 * D_REL);
    ax += v0.x; ay += v0.y;
    bx += v1.x; by += v1.y;
  }
  if (e < end) {
    int c0 = sorted_col[e];
    float2 v0 = *(const float2*)(base + (size_t)c0 * D_REL);
    ax += v0.x; ay += v0.y;
  }
  float wgt = inv_deg[wave];
  float2 o;
  o.x = (ax + bx) * wgt;
  o.y = (ay + by) * wgt;
  *(float2*)(dst + (size_t)wave * D_REL + lane * 2) = o;
}

extern "C" void kernel_launch(void* const* d_in, const int* in_sizes, int n_in,
                              void* d_out, int out_size, void* d_ws, size_t ws_size,
                              hipStream_t stream) {
  const float* x_src = (const float*)d_in[0];
  // d_in[1] = x_dst, d_in[3] = W_dst: dead (dst_proj is deleted in reference)
  const float* W_src = (const float*)d_in[2];
  const int* edge_row = (const int*)d_in[4];
  const int* edge_col = (const int*)d_in[5];

  const int M = in_sizes[0] / D_SRC;   // N_SRC = 100000
  const int N = in_sizes[1] / 64;      // N_DST = 100000
  const int E = in_sizes[4];           // 640000

  float* out = (float*)d_out;
  float* out_dst = out;                                  // [N, 128]
  float* out_src_proj = out + (size_t)N * D_REL;         // [M, 128]
  float* out_deg = out_src_proj + (size_t)M * D_REL;     // [N]

  // Workspace layout (256B-aligned slabs)
  char* ws = (char*)d_ws;
  size_t off = 0;
  auto alloc = [&](size_t bytes) {
    char* p = ws + off;
    off = (off + bytes + 255) & ~(size_t)255;
    return p;
  };
  int* cnt        = (int*)alloc((size_t)N * sizeof(int));
  int* row_ptr    = (int*)alloc((size_t)(N + 1) * sizeof(int));
  int* cursor     = (int*)alloc((size_t)N * sizeof(int));
  int* sorted_col = (int*)alloc((size_t)E * sizeof(int));
  float* inv_deg  = (float*)alloc((size_t)N * sizeof(float));
  int* block_sums = (int*)alloc(512 * sizeof(int));
  unsigned short* WT = (unsigned short*)alloc((size_t)D_REL * D_SRC * sizeof(unsigned short));
  unsigned short* src_bf = (unsigned short*)alloc((size_t)M * D_REL * sizeof(unsigned short));
  const bool use_bf = (ws_size >= off);

  const int scan_blocks = (N + SCAN_B - 1) / SCAN_B;  // 391 <= 512

  hipMemsetAsync(cnt, 0, (size_t)N * sizeof(int), stream);

  // W bf16, MFMA B-fragment order
  convert_wt<<<16, 256, 0, stream>>>(W_src, WT);

  // Degree
  deg_count<<<(E + 255) / 256, 256, 0, stream>>>(edge_row, E, cnt);

  // Exclusive scan cnt -> row_ptr (+ deg/inv_deg fused); cursor = row_ptr
  scan1<<<scan_blocks, SCAN_B, 0, stream>>>(cnt, N, row_ptr, block_sums,
                                            out_deg, inv_deg);
  scan2<<<1, 512, 0, stream>>>(block_sums, scan_blocks);
  scan3<<<scan_blocks, SCAN_B, 0, stream>>>(row_ptr, block_sums, cursor, N, E);

  // CSR scatter
  scatter_edges<<<(E + 255) / 256, 256, 0, stream>>>(edge_row, edge_col, cursor,
                                                     sorted_col, E);

  // MFMA GEMM (fused fp32->bf16 cvt): src_proj fp32 + bf16 copy for the gather
  gemm_mfma<<<(M + GBM - 1) / GBM, 512, 0, stream>>>(
      x_src, WT, out_src_proj, src_bf, M, use_bf ? 1 : 0);

  // Gather-aggregate: 1 wave per dst row, 4 edges/iter
  if (use_bf) {
    aggregate_csr_bf16<<<(N + 3) / 4, 256, 0, stream>>>(row_ptr, sorted_col, src_bf,
                                                        inv_deg, out_dst, N);
  } else {
    aggregate_csr<<<(N + 3) / 4, 256, 0, stream>>>(row_ptr, sorted_col, out_src_proj,
                                                   inv_deg, out_dst, N);
  }
}